// Round 18
// baseline (689.516 us; speedup 1.0000x reference)
//
#include <hip/hip_runtime.h>

#define T_SZ 12
#define R_WG 16
#define NTHR 1024
#define NWG  512   // 8192/16

typedef float  vf4 __attribute__((ext_vector_type(4)));
typedef int    vi4 __attribute__((ext_vector_type(4)));
typedef __bf16 vbf8 __attribute__((ext_vector_type(8)));

__device__ __forceinline__ float sigm(float x){ return 1.f/(1.f+__expf(-x)); }
__device__ __forceinline__ float tanh_f(float x){
  float e=__expf(2.f*x); return 1.f - 2.f/(e+1.f);
}
__device__ __forceinline__ unsigned short bf_hi(float f){
  return __builtin_bit_cast(unsigned short,(__bf16)f);
}
__device__ __forceinline__ float bf_f(unsigned short h){
  return __uint_as_float(((unsigned int)h)<<16);
}
__device__ __forceinline__ vf4 mfma16(vi4 a, vi4 b, vf4 c){
  return __builtin_amdgcn_mfma_f32_16x16x32_bf16(
      __builtin_bit_cast(vbf8,a), __builtin_bit_cast(vbf8,b), c, 0, 0, 0);
}
__device__ __forceinline__ vi4 g16(const char* p){ return *(const vi4*)p; }

// split-bf16 h slots: slot*4096 + [split +2048] + (row*8 + ((k>>3)^(row&7)))*16 + (k&7)*2
// slots: 0=h_tsa, 1..8=X fused nodes, 9=h_ts, 10=R (qk fp32 / hbar), 11..18=Y raw nodes
__device__ __forceinline__ void a_read(const char* h9,int slot,int ks,int arow,int kb,vi4& Ah,vi4& Al){
  int blk=((ks<<2)+kb)^(arow&7);
  const char* p=h9+slot*4096+(arow*8+blk)*16;
  Ah=*(const vi4*)p; Al=*(const vi4*)(p+2048);
}
__device__ __forceinline__ void h9_w1(char* h9,int slot,int row,int k,float v){
  int off=slot*4096+(row*8+((k>>3)^(row&7)))*16+(k&7)*2;
  unsigned short hi=bf_hi(v);
  *(unsigned short*)(h9+off)=hi;
  *(unsigned short*)(h9+off+2048)=bf_hi(v-bf_f(hi));
}
// write 4 consecutive k (k0 multiple of 4, same 8-k block): packed 8B hi + 8B lo
__device__ __forceinline__ void h9_w4c(char* h9,int slot,int row,int k0,vf4 v){
  int off=slot*4096+(row*8+((k0>>3)^(row&7)))*16+(k0&7)*2;
  unsigned short h0=bf_hi(v[0]),h1=bf_hi(v[1]),h2=bf_hi(v[2]),h3=bf_hi(v[3]);
  uint2 hv; hv.x=(unsigned)h0|((unsigned)h1<<16); hv.y=(unsigned)h2|((unsigned)h3<<16);
  *(uint2*)(h9+off)=hv;
  uint2 lv;
  lv.x=(unsigned)bf_hi(v[0]-bf_f(h0))|((unsigned)bf_hi(v[1]-bf_f(h1))<<16);
  lv.y=(unsigned)bf_hi(v[2]-bf_f(h2))|((unsigned)bf_hi(v[3]-bf_f(h3))<<16);
  *(uint2*)(h9+off+2048)=lv;
}
__device__ __forceinline__ float h9_rd(const char* h9,int slot,int row,int k){
  int off=slot*4096+(row*8+((k>>3)^(row&7)))*16+(k&7)*2;
  return bf_f(*(const unsigned short*)(h9+off))+bf_f(*(const unsigned short*)(h9+off+2048));
}

struct Ptrs {
  const unsigned short* Wm; const unsigned short* Wa; const unsigned short* Xf;
  const float* Fbp; const float* bqk; const float* f1b;
  const float* m1w; const float* m1b; const float* m2w; const float* m2b;
  float* out;
};

__global__ __launch_bounds__(NTHR,8) void fused_kernel(Ptrs P){
  __shared__ __align__(16) char  h9[77824];     // 19 slots x 4KB
  __shared__ __align__(16) float pbuf[128];

  const int tid=threadIdx.x;
  const int r0=blockIdx.x*R_WG;
  const int w=tid>>6, ln=tid&63;                 // 16 waves
  const int role=w>>2, cb=w&3;
  const int arow=ln&15, kb=ln>>4;
  const int rowL=ln&15;                          // batch row owned (swapped C)
  const int u_w=(w>>2)*16 + kb*4 + (w&3);        // LSTM u owned (1 u-block per wave)
  const int ub=cb*16 + kb*4;                     // attn u base (4 consecutive)
  const char* Wmb=(const char*)P.Wm;
  const char* awb=(const char*)P.Wa + ((size_t)cb)*4096 + (size_t)ln*16;
  const char* Xfb=(const char*)P.Xf + (size_t)(r0+arow)*9*24*32;
  float* qkf=(float*)(h9+10*4096);               // region R as fp32 qk

  const vf4 bqk4=*(const vf4*)(P.bqk+ub);
  const vf4 bF4 =*(const vf4*)(P.Fbp+ub);
  const vf4 bf14=*(const vf4*)(P.f1b+ub);

  float cst[9];
  #pragma unroll
  for(int l=0;l<9;l++) cst[l]=0.f;

  for(int i=tid;i<77824/16;i+=NTHR) ((vi4*)h9)[i]=(vi4){0,0,0,0};
  __syncthreads();   // zeros visible

  auto attn_gemm=[&](int cidx,int slot,vf4 acc)->vf4{
    const char* Wc=awb + (size_t)cidx*16384;
    vi4 Bh,Bl;
    vi4 W0=g16(Wc),W1=g16(Wc+1024),W2=g16(Wc+2048),W3=g16(Wc+3072);
    a_read(h9,slot,0,arow,kb,Bh,Bl);
    acc=mfma16(W0,Bh,acc); acc=mfma16(W0,Bl,acc); acc=mfma16(W1,Bh,acc);
    a_read(h9,slot,1,arow,kb,Bh,Bl);
    acc=mfma16(W2,Bh,acc); acc=mfma16(W2,Bl,acc); acc=mfma16(W3,Bh,acc);
    return acc;
  };

  for(int t=0;t<T_SZ;t++){
    // ===== 9 LSTMs, ZERO inner barriers: reads {0,1..8} / writes {9,11..18} disjoint =====
    // Each wave owns 1 u-block (16 gates x 16 rows); frag window = [lt][w>>1] + (w&1)*1024.
    #pragma unroll
    for(int l=0;l<9;l++){
      const int slotA=(l==0)?0:l;       // fused input
      const int slotW=(l==0)?9:(10+l);  // raw output
      const char* Wl=Wmb + (((size_t)(l*12+t)*8 + (w>>1))*12288) + (size_t)(w&1)*1024 + (size_t)ln*16;
      vf4 a0={0,0,0,0};
      vi4 Bh,Bl,Wh,Wlo;
      // ks0
      Wh=g16(Wl); Wlo=g16(Wl+2048);
      a_read(h9,slotA,0,arow,kb,Bh,Bl);
      a0=mfma16(Wh,Bh,a0); a0=mfma16(Wh,Bl,a0); a0=mfma16(Wlo,Bh,a0);
      // ks1
      Wh=g16(Wl+4096); Wlo=g16(Wl+6144);
      a_read(h9,slotA,1,arow,kb,Bh,Bl);
      a0=mfma16(Wh,Bh,a0); a0=mfma16(Wh,Bl,a0); a0=mfma16(Wlo,Bh,a0);
      // ks2: B = [x(16) | bias-1 | 0] pre-split frags
      Wh=g16(Wl+8192); Wlo=g16(Wl+10240);
      if(kb<2){
        const char* xp=Xfb + (size_t)(l*24 + t*2 + kb)*32;
        Bh=g16(xp); Bl=g16(xp+16);
      } else if(kb==2){ Bh=(vi4){0x3F80,0,0,0}; Bl=(vi4){0,0,0,0}; }
      else            { Bh=(vi4){0,0,0,0};     Bl=(vi4){0,0,0,0}; }
      a0=mfma16(Wh,Bh,a0); a0=mfma16(Wh,Bl,a0); a0=mfma16(Wlo,Bh,a0);
      // nonlin: gates i,f,g,o in acc[0..3] for (rowL, u_w)
      {
        float iv=sigm(a0[0]), fv=sigm(a0[1]), gv=tanh_f(a0[2]), ov=sigm(a0[3]);
        float c2=fv*cst[l]+iv*gv;
        cst[l]=c2;
        h9_w1(h9,slotW,rowL,u_w,ov*tanh_f(c2));
      }
    }
    __syncthreads();   // b2: all raw h (Y, slot9) visible

    const bool dofuse=(t<T_SZ-1);
    vf4 gA,gB,gC;   // fusion results held in regs across phS/phH (role-dependent nodes)
    // ===== window 1, 4 roles: r0: phKQ+F1 ; r1: F2,F3 ; r2: F4,F5,F6 ; r3: F7,F8 =====
    #define FUSE(gn,slot) { \
      a_read(h9,slot,0,arow,kb,Bh,Bl); \
      gn=mfma16(W0,Bh,gn); gn=mfma16(W0,Bl,gn); gn=mfma16(W1,Bh,gn); \
      a_read(h9,slot,1,arow,kb,Bh,Bl); \
      gn=mfma16(W2,Bh,gn); gn=mfma16(W2,Bl,gn); gn=mfma16(W3,Bh,gn); }
    if(role==0){
      vf4 aq=attn_gemm(0, 9, bqk4);   // qk = h_ts@QKc + bqk, C[u][row]
      *(vf4*)(qkf + rowL*64 + ub) = aq;
      if(dofuse){
        vf4 fa=attn_gemm(3, 9, bf14);
        const char* Wc=awb + (size_t)4*16384;
        vi4 W0=g16(Wc),W1=g16(Wc+1024),W2=g16(Wc+2048),W3=g16(Wc+3072);
        vi4 Bh,Bl;
        gA=fa; FUSE(gA,11)
      }
    } else if(dofuse){
      vf4 fa=attn_gemm(3, 9, bf14);
      const char* Wc=awb + (size_t)4*16384;
      vi4 W0=g16(Wc),W1=g16(Wc+1024),W2=g16(Wc+2048),W3=g16(Wc+3072);
      vi4 Bh,Bl;
      if(role==1){ gA=fa; FUSE(gA,12) gB=fa; FUSE(gB,13) }
      else if(role==2){ gA=fa; FUSE(gA,14) gB=fa; FUSE(gB,15) gC=fa; FUSE(gC,16) }
      else { gA=fa; FUSE(gA,17) gB=fa; FUSE(gB,18) }
    }
    #undef FUSE
    __syncthreads();   // b3: qk visible; fusion g's safely in regs
    // ===== phS: scores + softmax -> pbuf, ALL 1024 threads (8 per (row,n); row=w) =====
    {
      const int sub=tid&7, pair=tid>>3;
      const int rr=pair>>3, nn=pair&7;   // rr == w
      const char* hp=h9+(11+nn)*4096;
      float s=0.f;
      {
        int kbl=sub;
        int blk=kbl^(rr&7);
        const char* pp=hp+(rr*8+blk)*16;
        vi4 hv=*(const vi4*)pp;
        vi4 lv=*(const vi4*)(pp+2048);
        const vf4* qkp=(const vf4*)(qkf+rr*64+kbl*8);
        vf4 q0=qkp[0], q1=qkp[1];
        #pragma unroll
        for(int e=0;e<4;e++){
          unsigned hw=((const unsigned*)&hv)[e], lw=((const unsigned*)&lv)[e];
          float w0=__uint_as_float(hw<<16)+__uint_as_float(lw<<16);
          float w1=__uint_as_float(hw&0xffff0000u)+__uint_as_float(lw&0xffff0000u);
          float qa=(e<2)? q0[e*2] : q1[(e-2)*2];
          float qb=(e<2)? q0[e*2+1] : q1[(e-2)*2+1];
          s+=w0*qa+w1*qb;
        }
      }
      s+=__shfl_xor(s,1); s+=__shfl_xor(s,2); s+=__shfl_xor(s,4);   // k-reduce (8 subs)
      float mx=s;
      mx=fmaxf(mx,__shfl_xor(mx,8));
      mx=fmaxf(mx,__shfl_xor(mx,16));
      mx=fmaxf(mx,__shfl_xor(mx,32));
      float e=__expf(s-mx);
      float sm=e;
      sm+=__shfl_xor(sm,8); sm+=__shfl_xor(sm,16); sm+=__shfl_xor(sm,32);
      if(sub==0) pbuf[pair]=e/sm;
    }
    __syncthreads();   // b4: p visible; all qkf reads done
    // ===== phH: hbar -> region R (split-bf16), 16 waves x 1 row =====
    {
      float sa=0.f;
      #pragma unroll
      for(int n=0;n<8;n++) sa+=pbuf[w*8+n]*h9_rd(h9,11+n,w,ln);
      h9_w1(h9,10,w,ln,sa);
    }
    __syncthreads();   // b5: hbar visible
    // ===== phC+phB (role0) -> slot0 ; X-writes from g-regs (all roles) =====
    #define WRX(gn,slot) { \
      gn[0]=fmaxf(gn[0],0.f); gn[1]=fmaxf(gn[1],0.f); \
      gn[2]=fmaxf(gn[2],0.f); gn[3]=fmaxf(gn[3],0.f); \
      h9_w4c(h9,slot,rowL,ub,gn); }
    if(role==0){
      vf4 acA=attn_gemm(1, 10, bF4);
      acA=attn_gemm(2, 9, acA);
      acA[0]=fmaxf(acA[0],0.f); acA[1]=fmaxf(acA[1],0.f);
      acA[2]=fmaxf(acA[2],0.f); acA[3]=fmaxf(acA[3],0.f);
      h9_w4c(h9,0,rowL,ub,acA);
      if(dofuse){ WRX(gA,1) }
    } else if(dofuse){
      if(role==1){ WRX(gA,2) WRX(gB,3) }
      else if(role==2){ WRX(gA,4) WRX(gB,5) WRX(gC,6) }
      else { WRX(gA,7) WRX(gB,8) }
    }
    #undef WRX
    __syncthreads();   // b6: slot0 + X visible for next t / MLP
  }

  // ===== final MLP from slot0 (h_tsa) =====
  {
    float* hid=(float*)(h9+10*4096);   // region R dead
    if(tid<512){
      int rr=tid>>5, ii=tid&31;
      float h=P.m1b[ii];
      for(int k=0;k<64;k++) h+=h9_rd(h9,0,rr,k)*P.m1w[(size_t)ii*64+k];
      hid[rr*32+ii]=fmaxf(h,0.f);
    }
    __syncthreads();
    if(tid<R_WG){
      float s=P.m2b[0];
      for(int i=0;i<32;i++) s+=hid[tid*32+i]*P.m2w[i];
      P.out[r0+tid]=s;
    }
  }
}

// ---- prep: LSTM weight frags, lane-contiguous layout [lt][wave8][jj][lane][8] ----
__global__ void prep_wm(const float* eW, const float* eU, const float* e2W, const float* e2U,
                        const float* emb_w, const float* eb_ih, const float* eb_hh,
                        const float* e2b_ih, const float* e2b_hh, const float* emb_b,
                        unsigned short* dst){
  int id=blockIdx.x*256+threadIdx.x;
  if(id>=108*3*16*64) return;
  int lane=id&63;
  int q=id>>6;
  int wnt=q&15;
  int q2=q>>4;
  int ks=q2%3;
  int lt=q2/3;
  int LL=lt/12, t=lt%12;
  int c15=lane&15;
  int u=(wnt>>2)*16+(c15>>2)*4+(wnt&3);
  int gt=c15&3;
  int jg=gt*64+u;
  const float* Whh=(LL==0)? eU+((size_t)t*256+jg)*64 : e2U+(((size_t)(LL-1)*12+t)*256+jg)*64;
  const float* Wih=(LL==0)? eW+((size_t)t*256+jg)*32 : e2W+(((size_t)(LL-1)*12+t)*256+jg)*32;
  float bsum;
  {
    float bi=(LL==0)? eb_ih[t*256+jg] : e2b_ih[((LL-1)*12+t)*256+jg];
    float bh=(LL==0)? eb_hh[t*256+jg] : e2b_hh[((LL-1)*12+t)*256+jg];
    float s=bi+bh;
    for(int i=0;i<32;i++) s+=Wih[i]*emb_b[i];
    bsum=s;
  }
  int wv=wnt>>1, p=wnt&1;
  size_t base_hi=(((size_t)lt*8+wv)*12 + (4*ks+p  ))*512 + (size_t)lane*8;
  size_t base_lo=(((size_t)lt*8+wv)*12 + (4*ks+2+p))*512 + (size_t)lane*8;
  #pragma unroll
  for(int j=0;j<8;j++){
    int k=ks*32+(lane>>4)*8+j;
    float v;
    if(k<64) v=Whh[k];
    else if(k<80){
      int kx=k-64; float s=0.f;
      for(int i=0;i<32;i++) s+=Wih[i]*emb_w[i*16+kx];
      v=s;
    } else if(k==80) v=bsum;
    else v=0.f;
    unsigned short hi=bf_hi(v), lo=bf_hi(v-bf_f(hi));
    dst[base_hi+j]=hi;
    dst[base_lo+j]=lo;
  }
}

// ---- prep: 5 attention/fusion chunks, layout [cidx][colblk][q][lane][8], + Fbp + bqk ----
// cidx: 0=QKc(0.125*Qw.T@Kw), 1=VFc(FwA@Vw), 2=FBc, 3=F1Bc, 4=F1Ac
__global__ void prep_attw(const float* Qw, const float* Qb, const float* Kw,
                          const float* Vw, const float* Vb,
                          const float* Fw, const float* Fb, const float* f1w,
                          unsigned short* dst, float* Fbp, float* bqk){
  int id=blockIdx.x*256+threadIdx.x;
  if(id<5120){
    int cidx=id>>10;
    int rem=id&1023;
    int block=rem>>6;
    int lane=rem&63;
    int ks=(block>>1)&1, s=block&1;
    int cb=block>>2;
    int qq=(ks<<1)|s;
    int col=cb*16+(lane&15);
    size_t base=(((size_t)cidx*4+cb)*4 + qq)*512 + (size_t)lane*8;
    #pragma unroll
    for(int j=0;j<8;j++){
      int k=ks*32+(lane>>4)*8+j;
      float v;
      if(cidx==0){ float sv=0.f; for(int m=0;m<64;m++) sv+=Qw[m*64+k]*Kw[m*64+col]; v=sv*0.125f; }
      else if(cidx==1){ float sv=0.f; for(int m=0;m<64;m++) sv+=Fw[col*128+m]*Vw[m*64+k]; v=sv; }
      else if(cidx==2) v=Fw[col*128+64+k];
      else if(cidx==3) v=f1w[col*128+64+k];
      else             v=f1w[col*128+k];
      unsigned short hi=bf_hi(v);
      dst[base+j] = (s==0)? hi : bf_hi(v-bf_f(hi));
    }
  } else if(id<5184){
    int u=id-5120;
    float s=Fb[u];
    for(int m=0;m<64;m++) s+=Fw[u*128+m]*Vb[m];
    Fbp[u]=s;
  } else if(id<5248){
    int m=id-5184;
    float s=0.f;
    for(int u=0;u<64;u++) s+=Qb[u]*Kw[u*64+m];
    bqk[m]=s*0.125f;
  }
}

// ---- prep: x B-fragments pre-split: [b][src 0..8][t][kb]{hi 16B, lo 16B} ----
__global__ void prep_xf(const float* ts, const float* gts, unsigned short* xf){
  int id=blockIdx.x*256+threadIdx.x;
  if(id>=8192*9*24) return;
  int kb=id&1;
  int t=(id>>1)%12;
  int q=id/24;
  int src=q%9;
  int b=q/9;
  const float* s=(src==0)? ts+(size_t)b*192+(size_t)t*16+kb*8
                         : gts+(size_t)b*1536+(size_t)(src-1)*192+(size_t)t*16+kb*8;
  unsigned short* d=xf+(size_t)id*16;
  #pragma unroll
  for(int j=0;j<8;j++){
    float f=s[j];
    unsigned short hi=bf_hi(f);
    d[j]=hi;
    d[8+j]=bf_hi(f-bf_f(hi));
  }
}

extern "C" void kernel_launch(void* const* d_in, const int* in_sizes, int n_in,
                              void* d_out, int out_size, void* d_ws, size_t ws_size,
                              hipStream_t stream){
  const float* ts      =(const float*)d_in[0];
  const float* gts     =(const float*)d_in[1];
  const float* emb_w   =(const float*)d_in[2];
  const float* emb_b   =(const float*)d_in[3];
  const float* attQ_w  =(const float*)d_in[4];
  const float* attQ_b  =(const float*)d_in[5];
  const float* attK_w  =(const float*)d_in[6];
  // d_in[7] attK_b: softmax-invariant, unused
  const float* attV_w  =(const float*)d_in[8];
  const float* attV_b  =(const float*)d_in[9];
  const float* attF_w  =(const float*)d_in[10];
  const float* attF_b  =(const float*)d_in[11];
  const float* fuse1_w =(const float*)d_in[12];
  const float* fuse1_b =(const float*)d_in[13];
  const float* enc_Wih =(const float*)d_in[14];
  const float* enc_Whh =(const float*)d_in[15];
  const float* enc_bih =(const float*)d_in[16];
  const float* enc_bhh =(const float*)d_in[17];
  const float* enc2_Wih=(const float*)d_in[18];
  const float* enc2_Whh=(const float*)d_in[19];
  const float* enc2_bih=(const float*)d_in[20];
  const float* enc2_bhh=(const float*)d_in[21];
  const float* mlp1_w  =(const float*)d_in[22];
  const float* mlp1_b  =(const float*)d_in[23];
  const float* mlp2_w  =(const float*)d_in[24];
  const float* mlp2_b  =(const float*)d_in[25];

  char* ws=(char*)d_ws;
  size_t off=0;
  unsigned short* Wm=(unsigned short*)(ws+off); off+=(size_t)108*6*8192*2;
  unsigned short* Wa=(unsigned short*)(ws+off); off+=(size_t)5*8192*2;
  float* Fbp=(float*)(ws+off); off+=64*4;
  float* bqk=(float*)(ws+off); off+=64*4;
  unsigned short* Xf=(unsigned short*)(ws+off); off+=(size_t)8192*9*24*16*2;

  prep_wm<<<(108*3*16*64+255)/256,256,0,stream>>>(enc_Wih,enc_Whh,enc2_Wih,enc2_Whh,emb_w,
                                                  enc_bih,enc_bhh,enc2_bih,enc2_bhh,emb_b,Wm);
  prep_attw<<<21,256,0,stream>>>(attQ_w,attQ_b,attK_w,attV_w,attV_b,attF_w,attF_b,fuse1_w,
                                 Wa,Fbp,bqk);
  prep_xf<<<(8192*9*24+255)/256,256,0,stream>>>(ts,gts,Xf);

  Ptrs P;
  P.Wm=Wm; P.Wa=Wa; P.Xf=Xf;
  P.Fbp=Fbp; P.bqk=bqk; P.f1b=fuse1_b;
  P.m1w=mlp1_w; P.m1b=mlp1_b; P.m2w=mlp2_w; P.m2b=mlp2_b;
  P.out=(float*)d_out;

  fused_kernel<<<NWG,NTHR,0,stream>>>(P);
}

// Round 19
// 424.702 us; speedup vs baseline: 1.6235x; 1.6235x over previous
//
#include <hip/hip_runtime.h>

#define T_SZ 12
#define R_WG 16
#define NTHR 512
#define NWG  512   // 8192/16

typedef float  vf4 __attribute__((ext_vector_type(4)));
typedef int    vi4 __attribute__((ext_vector_type(4)));
typedef __bf16 vbf8 __attribute__((ext_vector_type(8)));

__device__ __forceinline__ float sigm(float x){ return 1.f/(1.f+__expf(-x)); }
__device__ __forceinline__ float tanh_f(float x){
  float e=__expf(2.f*x); return 1.f - 2.f/(e+1.f);
}
__device__ __forceinline__ unsigned short bf_hi(float f){
  return __builtin_bit_cast(unsigned short,(__bf16)f);
}
__device__ __forceinline__ float bf_f(unsigned short h){
  return __uint_as_float(((unsigned int)h)<<16);
}
__device__ __forceinline__ vf4 mfma16(vi4 a, vi4 b, vf4 c){
  return __builtin_amdgcn_mfma_f32_16x16x32_bf16(
      __builtin_bit_cast(vbf8,a), __builtin_bit_cast(vbf8,b), c, 0, 0, 0);
}
__device__ __forceinline__ vi4 g16(const char* p){ return *(const vi4*)p; }

// split-bf16 h slots: slot*4096 + [split +2048] + (row*8 + ((k>>3)^(row&7)))*16 + (k&7)*2
// slots: 0=h_tsa, 1..8=X fused nodes, 9=h_ts, 10=R (qk fp32 / hbar), 11..18=Y raw nodes
__device__ __forceinline__ void a_read(const char* h9,int slot,int ks,int arow,int kb,vi4& Ah,vi4& Al){
  int blk=((ks<<2)+kb)^(arow&7);
  const char* p=h9+slot*4096+(arow*8+blk)*16;
  Ah=*(const vi4*)p; Al=*(const vi4*)(p+2048);
}
__device__ __forceinline__ void h9_w1(char* h9,int slot,int row,int k,float v){
  int off=slot*4096+(row*8+((k>>3)^(row&7)))*16+(k&7)*2;
  unsigned short hi=bf_hi(v);
  *(unsigned short*)(h9+off)=hi;
  *(unsigned short*)(h9+off+2048)=bf_hi(v-bf_f(hi));
}
__device__ __forceinline__ void h9_w2(char* h9,int slot,int row,int k0,float v0,float v1){
  int off=slot*4096+(row*8+((k0>>3)^(row&7)))*16+(k0&7)*2;
  unsigned short h0=bf_hi(v0),h1=bf_hi(v1);
  *(unsigned*)(h9+off)=(unsigned)h0|((unsigned)h1<<16);
  *(unsigned*)(h9+off+2048)=(unsigned)bf_hi(v0-bf_f(h0))|((unsigned)bf_hi(v1-bf_f(h1))<<16);
}
// write 4 consecutive k (k0 multiple of 4, same 8-k block): packed 8B hi + 8B lo
__device__ __forceinline__ void h9_w4c(char* h9,int slot,int row,int k0,vf4 v){
  int off=slot*4096+(row*8+((k0>>3)^(row&7)))*16+(k0&7)*2;
  unsigned short h0=bf_hi(v[0]),h1=bf_hi(v[1]),h2=bf_hi(v[2]),h3=bf_hi(v[3]);
  uint2 hv; hv.x=(unsigned)h0|((unsigned)h1<<16); hv.y=(unsigned)h2|((unsigned)h3<<16);
  *(uint2*)(h9+off)=hv;
  uint2 lv;
  lv.x=(unsigned)bf_hi(v[0]-bf_f(h0))|((unsigned)bf_hi(v[1]-bf_f(h1))<<16);
  lv.y=(unsigned)bf_hi(v[2]-bf_f(h2))|((unsigned)bf_hi(v[3]-bf_f(h3))<<16);
  *(uint2*)(h9+off+2048)=lv;
}
__device__ __forceinline__ float h9_rd(const char* h9,int slot,int row,int k){
  int off=slot*4096+(row*8+((k>>3)^(row&7)))*16+(k&7)*2;
  return bf_f(*(const unsigned short*)(h9+off))+bf_f(*(const unsigned short*)(h9+off+2048));
}

struct Ptrs {
  const unsigned short* Wm; const unsigned short* Wa; const unsigned short* Xf;
  const float* Fbp; const float* bqk; const float* f1b;
  const float* m1w; const float* m1b; const float* m2w; const float* m2b;
  float* out;
};

__global__ __launch_bounds__(NTHR,4) void fused_kernel(Ptrs P){
  __shared__ __align__(16) char  h9[77824];     // 19 slots x 4KB
  __shared__ __align__(16) float pbuf[128];

  const int tid=threadIdx.x;
  const int r0=blockIdx.x*R_WG;
  const int w=tid>>6, ln=tid&63;
  const bool w4=(w<4);
  const int arow=ln&15, kb=ln>>4;
  const int rowL=ln&15;                                    // batch row owned (swapped C)
  const int uA=((2*w)>>2)*16 + (ln>>4)*4 + ((2*w)&3);      // LSTM u for a0 (a1 = uA+1)
  const int ub=(w&3)*16 + (ln>>4)*4;                       // attn u base (4 consecutive)
  const char* Wmb=(const char*)P.Wm;
  const char* awb=(const char*)P.Wa + ((size_t)(w&3))*4096 + (size_t)ln*16;
  const char* Xfb=(const char*)P.Xf + (size_t)(r0+arow)*9*24*32;
  float* qkf=(float*)(h9+10*4096);                         // region R as fp32 qk

  const vf4 bqk4=*(const vf4*)(P.bqk+ub);
  const vf4 bF4 =*(const vf4*)(P.Fbp+ub);
  const vf4 bf14=*(const vf4*)(P.f1b+ub);

  float cst[9][2];
  #pragma unroll
  for(int l=0;l<9;l++){ cst[l][0]=0.f; cst[l][1]=0.f; }

  for(int i=tid;i<77824/16;i+=NTHR) ((vi4*)h9)[i]=(vi4){0,0,0,0};
  __syncthreads();   // zeros visible

  auto attn_gemm=[&](int cidx,int slot,vf4 acc)->vf4{
    const char* Wc=awb + (size_t)cidx*16384;
    vi4 Bh,Bl;
    vi4 W0=g16(Wc),W1=g16(Wc+1024),W2=g16(Wc+2048),W3=g16(Wc+3072);
    a_read(h9,slot,0,arow,kb,Bh,Bl);
    acc=mfma16(W0,Bh,acc); acc=mfma16(W0,Bl,acc); acc=mfma16(W1,Bh,acc);
    a_read(h9,slot,1,arow,kb,Bh,Bl);
    acc=mfma16(W2,Bh,acc); acc=mfma16(W2,Bl,acc); acc=mfma16(W3,Bh,acc);
    return acc;
  };

  for(int t=0;t<T_SZ;t++){
    // ===== 9 LSTMs, ZERO inner barriers: reads {slot0,1..8} / writes {9,11..18} disjoint =====
    __builtin_amdgcn_s_setprio(1);
    #pragma unroll
    for(int l=0;l<9;l++){
      const int slotA=(l==0)?0:l;       // fused input
      const int slotW=(l==0)?9:(10+l);  // raw output
      const char* Wl=Wmb + (((size_t)(l*12+t)*8 + w)*12288) + (size_t)ln*16;
      vf4 a0={0,0,0,0},a1={0,0,0,0};
      vi4 Bh,Bl,Wh0,Wh1,Wl0,Wl1;
      // ks0: jj 0..3
      Wh0=g16(Wl); Wh1=g16(Wl+1024); Wl0=g16(Wl+2048); Wl1=g16(Wl+3072);
      a_read(h9,slotA,0,arow,kb,Bh,Bl);
      a0=mfma16(Wh0,Bh,a0); a0=mfma16(Wh0,Bl,a0); a0=mfma16(Wl0,Bh,a0);
      a1=mfma16(Wh1,Bh,a1); a1=mfma16(Wh1,Bl,a1); a1=mfma16(Wl1,Bh,a1);
      // ks1: jj 4..7
      {
        const char* Wk=Wl+4096;
        Wh0=g16(Wk); Wh1=g16(Wk+1024); Wl0=g16(Wk+2048); Wl1=g16(Wk+3072);
      }
      a_read(h9,slotA,1,arow,kb,Bh,Bl);
      a0=mfma16(Wh0,Bh,a0); a0=mfma16(Wh0,Bl,a0); a0=mfma16(Wl0,Bh,a0);
      a1=mfma16(Wh1,Bh,a1); a1=mfma16(Wh1,Bl,a1); a1=mfma16(Wl1,Bh,a1);
      // ks2: jj 8..11 ; B = [x(16) | bias-1 | 0] pre-split frags
      {
        const char* Wk=Wl+8192;
        Wh0=g16(Wk); Wh1=g16(Wk+1024); Wl0=g16(Wk+2048); Wl1=g16(Wk+3072);
      }
      if(kb<2){
        const char* xp=Xfb + (size_t)(l*24 + t*2 + kb)*32;
        Bh=g16(xp); Bl=g16(xp+16);
      } else if(kb==2){ Bh=(vi4){0x3F80,0,0,0}; Bl=(vi4){0,0,0,0}; }
      else            { Bh=(vi4){0,0,0,0};     Bl=(vi4){0,0,0,0}; }
      a0=mfma16(Wh0,Bh,a0); a0=mfma16(Wh0,Bl,a0); a0=mfma16(Wl0,Bh,a0);
      a1=mfma16(Wh1,Bh,a1); a1=mfma16(Wh1,Bl,a1); a1=mfma16(Wl1,Bh,a1);
      // nonlin: gates land directly in acc[0..3] (i,f,g,o)
      {
        float iv=sigm(a0[0]), fv=sigm(a0[1]), gv=tanh_f(a0[2]), ov=sigm(a0[3]);
        float c20=fv*cst[l][0]+iv*gv;
        cst[l][0]=c20;
        float h0v=ov*tanh_f(c20);
        iv=sigm(a1[0]); fv=sigm(a1[1]); gv=tanh_f(a1[2]); ov=sigm(a1[3]);
        float c21=fv*cst[l][1]+iv*gv;
        cst[l][1]=c21;
        float h1v=ov*tanh_f(c21);
        h9_w2(h9,slotW,rowL,uA,h0v,h1v);
      }
    }
    __builtin_amdgcn_s_setprio(0);
    __syncthreads();   // b2: all raw h (Y, slot9) visible

    const bool dofuse=(t<T_SZ-1);
    vf4 g1,g2,g3,g4,g5,g6,g7,g8;   // fusion results held in regs across phS/phH
    // ===== window 1 (rebalanced): w0-3: phKQ + f_ts + FUSE 1-3 ; w4-7: f_ts + FUSE 4-8 =====
    __builtin_amdgcn_s_setprio(1);
    #define FUSE(gn,slot) \
      a_read(h9,slot,0,arow,kb,Bh,Bl); \
      gn=mfma16(W0,Bh,gn); gn=mfma16(W0,Bl,gn); gn=mfma16(W1,Bh,gn); \
      a_read(h9,slot,1,arow,kb,Bh,Bl); \
      gn=mfma16(W2,Bh,gn); gn=mfma16(W2,Bl,gn); gn=mfma16(W3,Bh,gn);
    if(w4){
      vf4 aq=attn_gemm(0, 9, bqk4);   // qk = h_ts@QKc + bqk, C[u][row]
      *(vf4*)(qkf + rowL*64 + ub) = aq;
      if(dofuse){
        vf4 facc=attn_gemm(3, 9, bf14);
        const char* Wc=awb + (size_t)4*16384;
        vi4 W0=g16(Wc),W1=g16(Wc+1024),W2=g16(Wc+2048),W3=g16(Wc+3072);
        vi4 Bh,Bl;
        g1=facc;g2=facc;g3=facc;
        FUSE(g1,11) FUSE(g2,12) FUSE(g3,13)
      }
    } else if(dofuse){
      vf4 facc=attn_gemm(3, 9, bf14);
      const char* Wc=awb + (size_t)4*16384;
      vi4 W0=g16(Wc),W1=g16(Wc+1024),W2=g16(Wc+2048),W3=g16(Wc+3072);
      vi4 Bh,Bl;
      g4=facc;g5=facc;g6=facc;g7=facc;g8=facc;
      FUSE(g4,14) FUSE(g5,15) FUSE(g6,16) FUSE(g7,17) FUSE(g8,18)
    }
    #undef FUSE
    __builtin_amdgcn_s_setprio(0);
    __syncthreads();   // b3: qk visible; fusion g's safely in regs
    // ===== phS: scores + softmax -> pbuf, ALL 512 threads (4 threads per (row,n)) =====
    {
      const int sub=tid&3, pair=tid>>2;
      const int rr=pair>>3, nn=pair&7;
      const char* hp=h9+(11+nn)*4096;
      float s=0.f;
      #pragma unroll
      for(int ii=0;ii<2;ii++){
        int kbl=sub*2+ii;
        int blk=kbl^(rr&7);
        const char* pp=hp+(rr*8+blk)*16;
        vi4 hv=*(const vi4*)pp;
        vi4 lv=*(const vi4*)(pp+2048);
        const vf4* qkp=(const vf4*)(qkf+rr*64+kbl*8);
        vf4 q0=qkp[0], q1=qkp[1];
        #pragma unroll
        for(int e=0;e<4;e++){
          unsigned hw=((const unsigned*)&hv)[e], lw=((const unsigned*)&lv)[e];
          float w0=__uint_as_float(hw<<16)+__uint_as_float(lw<<16);
          float w1=__uint_as_float(hw&0xffff0000u)+__uint_as_float(lw&0xffff0000u);
          float qa=(e<2)? q0[e*2] : q1[(e-2)*2];
          float qb=(e<2)? q0[e*2+1] : q1[(e-2)*2+1];
          s+=w0*qa+w1*qb;
        }
      }
      s+=__shfl_xor(s,1); s+=__shfl_xor(s,2);        // k-reduce (4 subs)
      float mx=s;
      mx=fmaxf(mx,__shfl_xor(mx,4));
      mx=fmaxf(mx,__shfl_xor(mx,8));
      mx=fmaxf(mx,__shfl_xor(mx,16));
      float e=__expf(s-mx);
      float sm=e;
      sm+=__shfl_xor(sm,4); sm+=__shfl_xor(sm,8); sm+=__shfl_xor(sm,16);
      if(sub==0) pbuf[pair]=e/sm;
    }
    __syncthreads();   // b4: p visible; all qkf reads done
    // ===== phH: hbar -> region R (split-bf16), ALL 8 waves, 2 rows each =====
    {
      #pragma unroll
      for(int ri=0;ri<2;ri++){
        int row=w*2+ri;
        float sa=0.f;
        #pragma unroll
        for(int n=0;n<8;n++) sa+=pbuf[row*8+n]*h9_rd(h9,11+n,row,ln);
        h9_w1(h9,10,row,ln,sa);
      }
    }
    __syncthreads();   // b5: hbar visible
    // ===== phC+phB (w0-3) -> slot0 + X1-3 ; w4-7: X4-8 writes =====
    #define WRX(gn,slot) \
      gn[0]=fmaxf(gn[0],0.f); gn[1]=fmaxf(gn[1],0.f); \
      gn[2]=fmaxf(gn[2],0.f); gn[3]=fmaxf(gn[3],0.f); \
      h9_w4c(h9,slot,rowL,ub,gn);
    if(w4){
      __builtin_amdgcn_s_setprio(1);
      vf4 acA=attn_gemm(1, 10, bF4);
      acA=attn_gemm(2, 9, acA);
      __builtin_amdgcn_s_setprio(0);
      acA[0]=fmaxf(acA[0],0.f); acA[1]=fmaxf(acA[1],0.f);
      acA[2]=fmaxf(acA[2],0.f); acA[3]=fmaxf(acA[3],0.f);
      h9_w4c(h9,0,rowL,ub,acA);
      if(dofuse){ WRX(g1,1) WRX(g2,2) WRX(g3,3) }
    } else if(dofuse){
      WRX(g4,4) WRX(g5,5) WRX(g6,6) WRX(g7,7) WRX(g8,8)
    }
    #undef WRX
    __syncthreads();   // b6: slot0 + X visible for next t / MLP
  }

  // ===== final MLP from slot0 (h_tsa) =====
  {
    float* hid=(float*)(h9+10*4096);   // region R dead
    int rr=tid>>5, ii=tid&31;
    float h=P.m1b[ii];
    for(int k=0;k<64;k++) h+=h9_rd(h9,0,rr,k)*P.m1w[(size_t)ii*64+k];
    hid[rr*32+ii]=fmaxf(h,0.f);
    __syncthreads();
    if(tid<R_WG){
      float s=P.m2b[0];
      for(int i=0;i<32;i++) s+=hid[tid*32+i]*P.m2w[i];
      P.out[r0+tid]=s;
    }
  }
}

// ---- prep: LSTM weight frags, lane-contiguous layout [lt][wave][jj][lane][8] ----
__global__ void prep_wm(const float* eW, const float* eU, const float* e2W, const float* e2U,
                        const float* emb_w, const float* eb_ih, const float* eb_hh,
                        const float* e2b_ih, const float* e2b_hh, const float* emb_b,
                        unsigned short* dst){
  int id=blockIdx.x*256+threadIdx.x;
  if(id>=108*3*16*64) return;
  int lane=id&63;
  int q=id>>6;
  int wnt=q&15;
  int q2=q>>4;
  int ks=q2%3;
  int lt=q2/3;
  int LL=lt/12, t=lt%12;
  int c15=lane&15;
  int u=(wnt>>2)*16+(c15>>2)*4+(wnt&3);
  int gt=c15&3;
  int jg=gt*64+u;
  const float* Whh=(LL==0)? eU+((size_t)t*256+jg)*64 : e2U+(((size_t)(LL-1)*12+t)*256+jg)*64;
  const float* Wih=(LL==0)? eW+((size_t)t*256+jg)*32 : e2W+(((size_t)(LL-1)*12+t)*256+jg)*32;
  float bsum;
  {
    float bi=(LL==0)? eb_ih[t*256+jg] : e2b_ih[((LL-1)*12+t)*256+jg];
    float bh=(LL==0)? eb_hh[t*256+jg] : e2b_hh[((LL-1)*12+t)*256+jg];
    float s=bi+bh;
    for(int i=0;i<32;i++) s+=Wih[i]*emb_b[i];
    bsum=s;
  }
  int wv=wnt>>1, p=wnt&1;
  size_t base_hi=(((size_t)lt*8+wv)*12 + (4*ks+p  ))*512 + (size_t)lane*8;
  size_t base_lo=(((size_t)lt*8+wv)*12 + (4*ks+2+p))*512 + (size_t)lane*8;
  #pragma unroll
  for(int j=0;j<8;j++){
    int k=ks*32+(lane>>4)*8+j;
    float v;
    if(k<64) v=Whh[k];
    else if(k<80){
      int kx=k-64; float s=0.f;
      for(int i=0;i<32;i++) s+=Wih[i]*emb_w[i*16+kx];
      v=s;
    } else if(k==80) v=bsum;
    else v=0.f;
    unsigned short hi=bf_hi(v), lo=bf_hi(v-bf_f(hi));
    dst[base_hi+j]=hi;
    dst[base_lo+j]=lo;
  }
}

// ---- prep: 5 attention/fusion chunks, layout [cidx][colblk][q][lane][8], + Fbp + bqk ----
// cidx: 0=QKc(0.125*Qw.T@Kw), 1=VFc(FwA@Vw), 2=FBc, 3=F1Bc, 4=F1Ac
__global__ void prep_attw(const float* Qw, const float* Qb, const float* Kw,
                          const float* Vw, const float* Vb,
                          const float* Fw, const float* Fb, const float* f1w,
                          unsigned short* dst, float* Fbp, float* bqk){
  int id=blockIdx.x*256+threadIdx.x;
  if(id<5120){
    int cidx=id>>10;
    int rem=id&1023;
    int block=rem>>6;
    int lane=rem&63;
    int ks=(block>>1)&1, s=block&1;
    int cb=block>>2;
    int qq=(ks<<1)|s;
    int col=cb*16+(lane&15);
    size_t base=(((size_t)cidx*4+cb)*4 + qq)*512 + (size_t)lane*8;
    #pragma unroll
    for(int j=0;j<8;j++){
      int k=ks*32+(lane>>4)*8+j;
      float v;
      if(cidx==0){ float sv=0.f; for(int m=0;m<64;m++) sv+=Qw[m*64+k]*Kw[m*64+col]; v=sv*0.125f; }
      else if(cidx==1){ float sv=0.f; for(int m=0;m<64;m++) sv+=Fw[col*128+m]*Vw[m*64+k]; v=sv; }
      else if(cidx==2) v=Fw[col*128+64+k];
      else if(cidx==3) v=f1w[col*128+64+k];
      else             v=f1w[col*128+k];
      unsigned short hi=bf_hi(v);
      dst[base+j] = (s==0)? hi : bf_hi(v-bf_f(hi));
    }
  } else if(id<5184){
    int u=id-5120;
    float s=Fb[u];
    for(int m=0;m<64;m++) s+=Fw[u*128+m]*Vb[m];
    Fbp[u]=s;
  } else if(id<5248){
    int m=id-5184;
    float s=0.f;
    for(int u=0;u<64;u++) s+=Qb[u]*Kw[u*64+m];
    bqk[m]=s*0.125f;
  }
}

// ---- prep: x B-fragments pre-split: [b][src 0..8][t][kb]{hi 16B, lo 16B} ----
__global__ void prep_xf(const float* ts, const float* gts, unsigned short* xf){
  int id=blockIdx.x*256+threadIdx.x;
  if(id>=8192*9*24) return;
  int kb=id&1;
  int t=(id>>1)%12;
  int q=id/24;
  int src=q%9;
  int b=q/9;
  const float* s=(src==0)? ts+(size_t)b*192+(size_t)t*16+kb*8
                         : gts+(size_t)b*1536+(size_t)(src-1)*192+(size_t)t*16+kb*8;
  unsigned short* d=xf+(size_t)id*16;
  #pragma unroll
  for(int j=0;j<8;j++){
    float f=s[j];
    unsigned short hi=bf_hi(f);
    d[j]=hi;
    d[8+j]=bf_hi(f-bf_f(hi));
  }
}

extern "C" void kernel_launch(void* const* d_in, const int* in_sizes, int n_in,
                              void* d_out, int out_size, void* d_ws, size_t ws_size,
                              hipStream_t stream){
  const float* ts      =(const float*)d_in[0];
  const float* gts     =(const float*)d_in[1];
  const float* emb_w   =(const float*)d_in[2];
  const float* emb_b   =(const float*)d_in[3];
  const float* attQ_w  =(const float*)d_in[4];
  const float* attQ_b  =(const float*)d_in[5];
  const float* attK_w  =(const float*)d_in[6];
  // d_in[7] attK_b: softmax-invariant, unused
  const float* attV_w  =(const float*)d_in[8];
  const float* attV_b  =(const float*)d_in[9];
  const float* attF_w  =(const float*)d_in[10];
  const float* attF_b  =(const float*)d_in[11];
  const float* fuse1_w =(const float*)d_in[12];
  const float* fuse1_b =(const float*)d_in[13];
  const float* enc_Wih =(const float*)d_in[14];
  const float* enc_Whh =(const float*)d_in[15];
  const float* enc_bih =(const float*)d_in[16];
  const float* enc_bhh =(const float*)d_in[17];
  const float* enc2_Wih=(const float*)d_in[18];
  const float* enc2_Whh=(const float*)d_in[19];
  const float* enc2_bih=(const float*)d_in[20];
  const float* enc2_bhh=(const float*)d_in[21];
  const float* mlp1_w  =(const float*)d_in[22];
  const float* mlp1_b  =(const float*)d_in[23];
  const float* mlp2_w  =(const float*)d_in[24];
  const float* mlp2_b  =(const float*)d_in[25];

  char* ws=(char*)d_ws;
  size_t off=0;
  unsigned short* Wm=(unsigned short*)(ws+off); off+=(size_t)108*6*8192*2;
  unsigned short* Wa=(unsigned short*)(ws+off); off+=(size_t)5*8192*2;
  float* Fbp=(float*)(ws+off); off+=64*4;
  float* bqk=(float*)(ws+off); off+=64*4;
  unsigned short* Xf=(unsigned short*)(ws+off); off+=(size_t)8192*9*24*16*2;

  prep_wm<<<(108*3*16*64+255)/256,256,0,stream>>>(enc_Wih,enc_Whh,enc2_Wih,enc2_Whh,emb_w,
                                                  enc_bih,enc_bhh,enc2_bih,enc2_bhh,emb_b,Wm);
  prep_attw<<<21,256,0,stream>>>(attQ_w,attQ_b,attK_w,attV_w,attV_b,attF_w,attF_b,fuse1_w,
                                 Wa,Fbp,bqk);
  prep_xf<<<(8192*9*24+255)/256,256,0,stream>>>(ts,gts,Xf);

  Ptrs P;
  P.Wm=Wm; P.Wa=Wa; P.Xf=Xf;
  P.Fbp=Fbp; P.bqk=bqk; P.f1b=fuse1_b;
  P.m1w=mlp1_w; P.m1b=mlp1_b; P.m2w=mlp2_w; P.m2b=mlp2_b;
  P.out=(float*)d_out;

  fused_kernel<<<NWG,NTHR,0,stream>>>(P);
}